// Round 2
// baseline (234.115 us; speedup 1.0000x reference)
//
#include <hip/hip_runtime.h>

#define IMG   256
#define IMG2  65536
#define NB    64
#define NB2   128

typedef float v4f __attribute__((ext_vector_type(4)));

__device__ __forceinline__ void nt_store4(float* p, float x, float y, float z, float w) {
    v4f v = {x, y, z, w};
    __builtin_nontemporal_store(v, (v4f*)p);
}

// Block counts per type (all blocks 256 threads):
//   crops S=8  (g=32): 2048   src = cid>>5, ci = cid&31
//   crops S=16 (g=16): 1024
//   crops S=32 (g=8):  512
//   label:             4096   b = lid>>6, row-group = lid&63 (4 rows)
// Total 7680 = 512*15. Interleave 7 crops + 8 label per 15 consecutive
// blockIdx values so HBM reads (label: seg streams) and HBM writes
// (crops: 100 MB output) overlap instead of running as two phases.
#define NBLK_C8   2048
#define NBLK_C16  1024
#define NBLK_C32  512
#define NBLK_LBL  4096
#define NBLK_ALL  (NBLK_C8 + NBLK_C16 + NBLK_C32 + NBLK_LBL)

// ---------------------------------------------------------------------------
// crops: one block per (src image, cell-row ci). Both the unshifted (A) and
// shifted (B) cells are contiguous S x S image blocks at base max(c*S-4,0).
// Sweep 1: float4 min/max stats (shuffle + tiny-LDS reduce).
// Sweep 2: re-read (cache-hot) + normalize + nontemporal float4 stores.
// ---------------------------------------------------------------------------
template <int S>
__device__ __forceinline__ void crops_cell_row(
    const float* __restrict__ img,
    const float* __restrict__ heat,
    float* __restrict__ out,
    int src, int ci,
    float (*s_red)[32][4],
    float (*s_fin)[4]) {
    constexpr int G   = IMG / S;
    constexpr int L   = (S == 8) ? 3 : (S == 16) ? 4 : 5;
    constexpr int CPL = S / 4;

    const int tid = threadIdx.x;
    const int w   = tid >> 6;
    const int l   = tid & 63;
    const int cj  = l >> (L - 2);
    const int o   = (l & (CPL - 1)) * 4;

    const int rA   = ci * S;
    const int rB   = (ci == 0) ? 0 : rA - 4;
    const int colA = cj * S + o;
    const int colB = ((cj == 0) ? 0 : cj * S - 4) + o;

    const float* __restrict__ sp = img + (size_t)src * IMG2;

    float mnA = 3.4e38f, mxA = -3.4e38f, mnB = 3.4e38f, mxB = -3.4e38f;
#pragma unroll
    for (int k = 0; k < S / 4; ++k) {
        const int r = w + 4 * k;
        const float4 a  = *(const float4*)(sp + (rA + r) * IMG + colA);
        const float4 bq = *(const float4*)(sp + (rB + r) * IMG + colB);
        mnA = fminf(mnA, fminf(fminf(a.x, a.y), fminf(a.z, a.w)));
        mxA = fmaxf(mxA, fmaxf(fmaxf(a.x, a.y), fmaxf(a.z, a.w)));
        mnB = fminf(mnB, fminf(fminf(bq.x, bq.y), fminf(bq.z, bq.w)));
        mxB = fmaxf(mxB, fmaxf(fmaxf(bq.x, bq.y), fmaxf(bq.z, bq.w)));
    }
#pragma unroll
    for (int off = 1; off < CPL; off <<= 1) {
        mnA = fminf(mnA, __shfl_xor(mnA, off, 64));
        mxA = fmaxf(mxA, __shfl_xor(mxA, off, 64));
        mnB = fminf(mnB, __shfl_xor(mnB, off, 64));
        mxB = fmaxf(mxB, __shfl_xor(mxB, off, 64));
    }
    if ((l & (CPL - 1)) == 0) {
        float* p = &s_red[w][cj][0];
        p[0] = mnA; p[1] = mxA; p[2] = mnB; p[3] = mxB;
    }
    __syncthreads();
    if (tid < G) {
        float a0 = 3.4e38f, a1 = -3.4e38f, b0 = 3.4e38f, b1 = -3.4e38f;
#pragma unroll
        for (int ww = 0; ww < 4; ++ww) {
            a0 = fminf(a0, s_red[ww][tid][0]);
            a1 = fmaxf(a1, s_red[ww][tid][1]);
            b0 = fminf(b0, s_red[ww][tid][2]);
            b1 = fmaxf(b1, s_red[ww][tid][3]);
        }
        const float hA = heat[(size_t)src * G * G + ci * G + tid];
        const float hB = heat[(size_t)(src + NB) * G * G + ci * G + tid];
        s_fin[tid][0] = a0;
        s_fin[tid][1] = (hA > 0.5f ? 1.0f : 0.0f) / (a1 - a0 + 1e-5f);
        s_fin[tid][2] = b0;
        s_fin[tid][3] = (hB > 0.5f ? 1.0f : 0.0f) / (b1 - b0 + 1e-5f);
    }
    __syncthreads();
    const float fmnA = s_fin[cj][0], finvA = s_fin[cj][1];
    const float fmnB = s_fin[cj][2], finvB = s_fin[cj][3];

    float* __restrict__ dA = out + (size_t)src * IMG2;
    float* __restrict__ dB = out + (size_t)(src + NB) * IMG2;
#pragma unroll
    for (int k = 0; k < S / 4; ++k) {
        const int r = w + 4 * k;
        const float4 a  = *(const float4*)(sp + (rA + r) * IMG + colA);
        const float4 bq = *(const float4*)(sp + (rB + r) * IMG + colB);
        nt_store4(dA + (rA + r) * IMG + colA,
                  (a.x - fmnA) * finvA, (a.y - fmnA) * finvA,
                  (a.z - fmnA) * finvA, (a.w - fmnA) * finvA);
        nt_store4(dB + (rA + r) * IMG + colA,
                  (bq.x - fmnB) * finvB, (bq.y - fmnB) * finvB,
                  (bq.z - fmnB) * finvB, (bq.w - fmnB) * finvB);
    }
}

// ---------------------------------------------------------------------------
// label v3: one wave per row, 4 px per lane, float4 loads/stores. The +4
// column shift is an overlapping float4 load at min(v0+4,252) (16B-aligned;
// clamped lanes are fully masked). Pixels v0..v0+3 always share a heat cell
// (v0 multiple of 4, min cell width 8), so heat reads are scalar per lane.
// ---------------------------------------------------------------------------
__device__ __forceinline__ void label_rows(
    const float* __restrict__ heat8,
    const float* __restrict__ heat16,
    const float* __restrict__ heat32,
    const float* __restrict__ seg8,
    const float* __restrict__ seg16,
    const float* __restrict__ seg32,
    float* __restrict__ out,
    int b, int u0) {
    const int wave = threadIdx.x >> 6;
    const int lane = threadIdx.x & 63;
    const int u    = u0 + wave;
    const int v0   = lane << 2;
    const int vs   = min(v0 + 4, 252);   // shifted-load base, clamped

    float nu[4] = {0.f, 0.f, 0.f, 0.f};
    float de[4] = {0.f, 0.f, 0.f, 0.f};

    if (u0 >= 32 && u0 <= 248) {
        // fast: only preimage row i = u+4 exists for every scale
        const int i1 = u + 4;
#define SCALE_F(heat, seg, g, l, s)                                           \
        {                                                                     \
            const float* __restrict__ h1 = heat + b * (g * g);                \
            const float* __restrict__ h2 = heat + (NB + b) * (g * g);         \
            const float* __restrict__ r1 = seg + (size_t)b * IMG2 + u * IMG;  \
            const float* __restrict__ r2 =                                    \
                seg + (size_t)(NB + b) * IMG2 + i1 * IMG;                     \
            const float4 sd  = *(const float4*)(r1 + v0);                     \
            const float4 sg0 = *(const float4*)(r2 + v0);                     \
            const float4 sg1 = *(const float4*)(r2 + vs);                     \
            const float hd  = h1[(u >> l) * g + (v0 >> l)];                   \
            const float hg0 = h2[(i1 >> l) * g + (v0 >> l)];                  \
            const float hg1 = h2[(i1 >> l) * g + (vs >> l)];                  \
            const float md = (hd > 0.5f) ? 1.0f : 0.0f;                       \
            const float g0 = (hg0 > 0.5f) ? 1.0f : 0.0f;                      \
            const float g1 = (hg1 > 0.5f) ? 1.0f : 0.0f;                      \
            _Pragma("unroll")                                                 \
            for (int c = 0; c < 4; ++c) {                                     \
                const int v = v0 + c;                                         \
                const float m0 = (v < (s)) ? g0 : 0.0f;                       \
                const float m1 = (v >= (s) - 4 && v <= 251) ? g1 : 0.0f;      \
                float x = ((const float*)&sd)[c] * md;                        \
                x = fmaf(m0, ((const float*)&sg0)[c], x);                     \
                x = fmaf(m1, ((const float*)&sg1)[c], x);                     \
                nu[c] += x;                                                   \
                de[c] += md + m0 + m1;                                        \
            }                                                                 \
        }
        SCALE_F(heat32, seg32, 32, 3, 8)
        SCALE_F(heat16, seg16, 16, 4, 16)
        SCALE_F(heat8,  seg8,  8,  5, 32)
#undef SCALE_F
    } else {
        // generic: full 2x2 preimage with masks
        const int i0  = u;
        const int i1c = min(u + 4, 255);
#define SCALE_G(heat, seg, g, l, s)                                           \
        {                                                                     \
            const float* __restrict__ h1 = heat + b * (g * g);                \
            const float* __restrict__ h2 = heat + (NB + b) * (g * g);         \
            const float* __restrict__ r1 = seg + (size_t)b * IMG2 + u * IMG;  \
            const float* __restrict__ ra =                                    \
                seg + (size_t)(NB + b) * IMG2 + i0 * IMG;                     \
            const float* __restrict__ rb =                                    \
                seg + (size_t)(NB + b) * IMG2 + i1c * IMG;                    \
            const float4 sd  = *(const float4*)(r1 + v0);                     \
            const float4 a0q = *(const float4*)(ra + v0);                     \
            const float4 a1q = *(const float4*)(ra + vs);                     \
            const float4 b0q = *(const float4*)(rb + v0);                     \
            const float4 b1q = *(const float4*)(rb + vs);                     \
            const float hd  = h1[(u >> l) * g + (v0 >> l)];                   \
            const float hA0 = h2[(i0 >> l) * g + (v0 >> l)];                  \
            const float hA1 = h2[(i0 >> l) * g + (vs >> l)];                  \
            const float hB0 = h2[(i1c >> l) * g + (v0 >> l)];                 \
            const float hB1 = h2[(i1c >> l) * g + (vs >> l)];                 \
            const float miA = (u < (s)) ? 1.0f : 0.0f;                        \
            const float miB = (u >= (s) - 4 && u <= 251) ? 1.0f : 0.0f;       \
            const float md  = (hd > 0.5f) ? 1.0f : 0.0f;                      \
            const float gA0 = miA * ((hA0 > 0.5f) ? 1.0f : 0.0f);             \
            const float gA1 = miA * ((hA1 > 0.5f) ? 1.0f : 0.0f);             \
            const float gB0 = miB * ((hB0 > 0.5f) ? 1.0f : 0.0f);             \
            const float gB1 = miB * ((hB1 > 0.5f) ? 1.0f : 0.0f);             \
            _Pragma("unroll")                                                 \
            for (int c = 0; c < 4; ++c) {                                     \
                const int v = v0 + c;                                         \
                const float mj0 = (v < (s)) ? 1.0f : 0.0f;                    \
                const float mj1 = (v >= (s) - 4 && v <= 251) ? 1.0f : 0.0f;   \
                const float w00 = gA0 * mj0, w01 = gA1 * mj1;                 \
                const float w10 = gB0 * mj0, w11 = gB1 * mj1;                 \
                float x = ((const float*)&sd)[c] * md;                        \
                x = fmaf(w00, ((const float*)&a0q)[c], x);                    \
                x = fmaf(w01, ((const float*)&a1q)[c], x);                    \
                x = fmaf(w10, ((const float*)&b0q)[c], x);                    \
                x = fmaf(w11, ((const float*)&b1q)[c], x);                    \
                nu[c] += x;                                                   \
                de[c] += md + w00 + w01 + w10 + w11;                          \
            }                                                                 \
        }
        SCALE_G(heat32, seg32, 32, 3, 8)
        SCALE_G(heat16, seg16, 16, 4, 16)
        SCALE_G(heat8,  seg8,  8,  5, 32)
#undef SCALE_G
    }

    nt_store4(out + (size_t)b * IMG2 + u * IMG + v0,
              nu[0] / (de[0] + 1e-10f), nu[1] / (de[1] + 1e-10f),
              nu[2] / (de[2] + 1e-10f), nu[3] / (de[3] + 1e-10f));
}

__global__ __launch_bounds__(256, 8) void fused_kernel(
    const float* __restrict__ img,
    const float* __restrict__ heat8,
    const float* __restrict__ heat16,
    const float* __restrict__ heat32,
    const float* __restrict__ seg8,
    const float* __restrict__ seg16,
    const float* __restrict__ seg32,
    float* __restrict__ out) {
    __shared__ float s_red[4][32][4];
    __shared__ float s_fin[32][4];

    float* crops32 = out;                           // (128,1,256,256) s=8
    float* crops16 = out + (size_t)NB2 * IMG2;      // s=16
    float* crops8  = out + (size_t)2 * NB2 * IMG2;  // s=32
    float* label   = out + (size_t)3 * NB2 * IMG2;  // (64,1,256,256)

    // Interleave: each group of 15 consecutive blocks = 7 crops + 8 label.
    // Keeps within-type ordering (locality) while mixing the read-heavy
    // label stream with the write-heavy crops stream across the whole run.
    const int bid = blockIdx.x;
    const int grp = bid / 15;
    const int rem = bid - grp * 15;

    if (rem < 7) {
        const int cid = grp * 7 + rem;              // 0 .. 3583
        if (cid < NBLK_C8) {
            crops_cell_row<8>(img, heat32, crops32, cid >> 5, cid & 31, s_red, s_fin);
        } else if (cid < NBLK_C8 + NBLK_C16) {
            const int t = cid - NBLK_C8;
            crops_cell_row<16>(img, heat16, crops16, t >> 4, t & 15, s_red, s_fin);
        } else {
            const int t = cid - (NBLK_C8 + NBLK_C16);
            crops_cell_row<32>(img, heat8, crops8, t >> 3, t & 7, s_red, s_fin);
        }
    } else {
        const int lid = grp * 8 + (rem - 7);        // 0 .. 4095
        label_rows(heat8, heat16, heat32, seg8, seg16, seg32, label,
                   lid >> 6, (lid & 63) << 2);
    }
}

extern "C" void kernel_launch(void* const* d_in, const int* in_sizes, int n_in,
                              void* d_out, int out_size, void* d_ws, size_t ws_size,
                              hipStream_t stream) {
    const float* img    = (const float*)d_in[0];
    const float* heat8  = (const float*)d_in[1];
    const float* heat16 = (const float*)d_in[2];
    const float* heat32 = (const float*)d_in[3];
    const float* seg8   = (const float*)d_in[4];
    const float* seg16  = (const float*)d_in[5];
    const float* seg32  = (const float*)d_in[6];

    fused_kernel<<<dim3(NBLK_ALL), 256, 0, stream>>>(
        img, heat8, heat16, heat32, seg8, seg16, seg32, (float*)d_out);
}

// Round 3
// 224.243 us; speedup vs baseline: 1.0440x; 1.0440x over previous
//
#include <hip/hip_runtime.h>

#define IMG   256
#define IMG2  65536
#define NB    64
#define NB2   128

// ---------------------------------------------------------------------------
// Grid layout: 13312 blocks x 256 threads = 1024 groups of 13
//   rem<9 : crops block (9216 total = 36864 waves, no barriers, no LDS)
//            waves [0,16384)      S=8  (g=32): wave = 4-cell strip
//            waves [16384,32768)  S=16 (g=16): wave = 1 cell
//            waves [32768,36864)  S=32 (g=8):  wave = 1 cell, 4 row-iters
//   rem>=9: label block (4096 total), 1 wave per output row
// Interleave keeps the read-heavy label stream and write-heavy crops stream
// co-resident across the whole kernel.
// ---------------------------------------------------------------------------
#define NBLK_ALL  13312

// ---------------------------------------------------------------------------
// crops, register-resident: per cell, both the unshifted (A) and shifted (B)
// source tiles are contiguous S x S blocks at row/col base max(c*S-4, 0).
// Each cell's min/max closes within one wave via shfl_xor butterflies, so the
// tile stays in registers: 1 read + reduce + normalize + 1 write. B output is
// stored at A's pixel position (matches reference).
// ---------------------------------------------------------------------------
__device__ __forceinline__ float4 norm4(float4 a, float mn, float inv) {
    float4 o;
    o.x = (a.x - mn) * inv; o.y = (a.y - mn) * inv;
    o.z = (a.z - mn) * inv; o.w = (a.w - mn) * inv;
    return o;
}

__device__ __forceinline__ void mm4(float4 a, float& mn, float& mx) {
    mn = fminf(mn, fminf(fminf(a.x, a.y), fminf(a.z, a.w)));
    mx = fmaxf(mx, fmaxf(fmaxf(a.x, a.y), fmaxf(a.z, a.w)));
}

// S=8: wave handles a 4-cell strip (8 rows x 32 cols) of one cell-row.
// lane = r*8 + cell*2 + half  ->  cell-mates differ in bits {0,3,4,5}.
__device__ __forceinline__ void crops_s8(
    const float* __restrict__ img, const float* __restrict__ heat,
    float* __restrict__ out, int wid) {
    const int l   = threadIdx.x & 63;
    const int src = wid >> 8;
    const int rem = wid & 255;
    const int ci  = rem >> 3;
    const int st  = rem & 7;

    const int r    = l >> 3;
    const int cj   = st * 4 + ((l >> 1) & 3);
    const int o    = (l & 1) * 4;
    const int rowA = ci * 8 + r;
    const int rowB = ((ci == 0) ? 0 : ci * 8 - 4) + r;
    const int colA = st * 32 + (l & 7) * 4;
    const int colB = ((cj == 0) ? 0 : cj * 8 - 4) + o;

    const float* __restrict__ sp = img + (size_t)src * IMG2;
    const float4 a  = *(const float4*)(sp + rowA * IMG + colA);
    const float4 bq = *(const float4*)(sp + rowB * IMG + colB);

    float mnA = 3.4e38f, mxA = -3.4e38f, mnB = 3.4e38f, mxB = -3.4e38f;
    mm4(a, mnA, mxA); mm4(bq, mnB, mxB);
#pragma unroll
    for (int k = 0; k < 4; ++k) {
        const int off = (k == 0) ? 1 : (4 << k);  // 1, 8, 16, 32
        mnA = fminf(mnA, __shfl_xor(mnA, off, 64));
        mxA = fmaxf(mxA, __shfl_xor(mxA, off, 64));
        mnB = fminf(mnB, __shfl_xor(mnB, off, 64));
        mxB = fmaxf(mxB, __shfl_xor(mxB, off, 64));
    }
    const float hA = heat[(size_t)src * 1024 + ci * 32 + cj];
    const float hB = heat[(size_t)(src + NB) * 1024 + ci * 32 + cj];
    const float invA = (hA > 0.5f ? 1.0f : 0.0f) / (mxA - mnA + 1e-5f);
    const float invB = (hB > 0.5f ? 1.0f : 0.0f) / (mxB - mnB + 1e-5f);

    const size_t p = (size_t)src * IMG2 + rowA * IMG + colA;
    *(float4*)(out + p)                      = norm4(a,  mnA, invA);
    *(float4*)(out + p + (size_t)NB * IMG2)  = norm4(bq, mnB, invB);
}

// S=16: wave = one 16x16 cell; lane = r*4 + quarter.
__device__ __forceinline__ void crops_s16(
    const float* __restrict__ img, const float* __restrict__ heat,
    float* __restrict__ out, int wid) {
    const int l   = threadIdx.x & 63;
    const int src = wid >> 8;
    const int rem = wid & 255;
    const int ci  = rem >> 4;
    const int cj  = rem & 15;

    const int r    = l >> 2;
    const int o    = (l & 3) * 4;
    const int rowA = ci * 16 + r;
    const int rowB = ((ci == 0) ? 0 : ci * 16 - 4) + r;
    const int colA = cj * 16 + o;
    const int colB = ((cj == 0) ? 0 : cj * 16 - 4) + o;

    const float* __restrict__ sp = img + (size_t)src * IMG2;
    const float4 a  = *(const float4*)(sp + rowA * IMG + colA);
    const float4 bq = *(const float4*)(sp + rowB * IMG + colB);

    float mnA = 3.4e38f, mxA = -3.4e38f, mnB = 3.4e38f, mxB = -3.4e38f;
    mm4(a, mnA, mxA); mm4(bq, mnB, mxB);
#pragma unroll
    for (int off = 1; off < 64; off <<= 1) {
        mnA = fminf(mnA, __shfl_xor(mnA, off, 64));
        mxA = fmaxf(mxA, __shfl_xor(mxA, off, 64));
        mnB = fminf(mnB, __shfl_xor(mnB, off, 64));
        mxB = fmaxf(mxB, __shfl_xor(mxB, off, 64));
    }
    const float hA = heat[(size_t)src * 256 + ci * 16 + cj];
    const float hB = heat[(size_t)(src + NB) * 256 + ci * 16 + cj];
    const float invA = (hA > 0.5f ? 1.0f : 0.0f) / (mxA - mnA + 1e-5f);
    const float invB = (hB > 0.5f ? 1.0f : 0.0f) / (mxB - mnB + 1e-5f);

    const size_t p = (size_t)src * IMG2 + rowA * IMG + colA;
    *(float4*)(out + p)                      = norm4(a,  mnA, invA);
    *(float4*)(out + p + (size_t)NB * IMG2)  = norm4(bq, mnB, invB);
}

// S=32: wave = one 32x32 cell, 4 row-iterations held in registers.
__device__ __forceinline__ void crops_s32(
    const float* __restrict__ img, const float* __restrict__ heat,
    float* __restrict__ out, int wid) {
    const int l   = threadIdx.x & 63;
    const int src = wid >> 6;
    const int rem = wid & 63;
    const int ci  = rem >> 3;
    const int cj  = rem & 7;

    const int r0   = l >> 3;
    const int o    = (l & 7) * 4;
    const int rA   = ci * 32;
    const int rB   = (ci == 0) ? 0 : rA - 4;
    const int colA = cj * 32 + o;
    const int colB = ((cj == 0) ? 0 : cj * 32 - 4) + o;

    const float* __restrict__ sp = img + (size_t)src * IMG2;
    float4 a[4], bq[4];
#pragma unroll
    for (int k = 0; k < 4; ++k) {
        const int r = r0 + 8 * k;
        a[k]  = *(const float4*)(sp + (rA + r) * IMG + colA);
        bq[k] = *(const float4*)(sp + (rB + r) * IMG + colB);
    }
    float mnA = 3.4e38f, mxA = -3.4e38f, mnB = 3.4e38f, mxB = -3.4e38f;
#pragma unroll
    for (int k = 0; k < 4; ++k) { mm4(a[k], mnA, mxA); mm4(bq[k], mnB, mxB); }
#pragma unroll
    for (int off = 1; off < 64; off <<= 1) {
        mnA = fminf(mnA, __shfl_xor(mnA, off, 64));
        mxA = fmaxf(mxA, __shfl_xor(mxA, off, 64));
        mnB = fminf(mnB, __shfl_xor(mnB, off, 64));
        mxB = fmaxf(mxB, __shfl_xor(mxB, off, 64));
    }
    const float hA = heat[(size_t)src * 64 + ci * 8 + cj];
    const float hB = heat[(size_t)(src + NB) * 64 + ci * 8 + cj];
    const float invA = (hA > 0.5f ? 1.0f : 0.0f) / (mxA - mnA + 1e-5f);
    const float invB = (hB > 0.5f ? 1.0f : 0.0f) / (mxB - mnB + 1e-5f);

    float* __restrict__ dA = out + (size_t)src * IMG2;
    float* __restrict__ dB = out + (size_t)(src + NB) * IMG2;
#pragma unroll
    for (int k = 0; k < 4; ++k) {
        const int r = r0 + 8 * k;
        *(float4*)(dA + (rA + r) * IMG + colA) = norm4(a[k],  mnA, invA);
        *(float4*)(dB + (rA + r) * IMG + colA) = norm4(bq[k], mnB, invB);
    }
}

// ---------------------------------------------------------------------------
// label: one wave per row, 4 px per lane, float4 loads/stores. The +4
// column shift is an overlapping float4 load at min(v0+4,252) (16B-aligned;
// clamped lanes are fully masked). Pixels v0..v0+3 always share a heat cell
// (v0 multiple of 4, min cell width 8), so heat reads are scalar per lane.
// ---------------------------------------------------------------------------
__device__ __forceinline__ void label_rows(
    const float* __restrict__ heat8,
    const float* __restrict__ heat16,
    const float* __restrict__ heat32,
    const float* __restrict__ seg8,
    const float* __restrict__ seg16,
    const float* __restrict__ seg32,
    float* __restrict__ out,
    int b, int u0) {
    const int wave = threadIdx.x >> 6;
    const int lane = threadIdx.x & 63;
    const int u    = u0 + wave;
    const int v0   = lane << 2;
    const int vs   = min(v0 + 4, 252);   // shifted-load base, clamped

    float nu[4] = {0.f, 0.f, 0.f, 0.f};
    float de[4] = {0.f, 0.f, 0.f, 0.f};

    if (u0 >= 32 && u0 <= 248) {
        // fast: only preimage row i = u+4 exists for every scale
        const int i1 = u + 4;
#define SCALE_F(heat, seg, g, l, s)                                           \
        {                                                                     \
            const float* __restrict__ h1 = heat + b * (g * g);                \
            const float* __restrict__ h2 = heat + (NB + b) * (g * g);         \
            const float* __restrict__ r1 = seg + (size_t)b * IMG2 + u * IMG;  \
            const float* __restrict__ r2 =                                    \
                seg + (size_t)(NB + b) * IMG2 + i1 * IMG;                     \
            const float4 sd  = *(const float4*)(r1 + v0);                     \
            const float4 sg0 = *(const float4*)(r2 + v0);                     \
            const float4 sg1 = *(const float4*)(r2 + vs);                     \
            const float hd  = h1[(u >> l) * g + (v0 >> l)];                   \
            const float hg0 = h2[(i1 >> l) * g + (v0 >> l)];                  \
            const float hg1 = h2[(i1 >> l) * g + (vs >> l)];                  \
            const float md = (hd > 0.5f) ? 1.0f : 0.0f;                       \
            const float g0 = (hg0 > 0.5f) ? 1.0f : 0.0f;                      \
            const float g1 = (hg1 > 0.5f) ? 1.0f : 0.0f;                      \
            _Pragma("unroll")                                                 \
            for (int c = 0; c < 4; ++c) {                                     \
                const int v = v0 + c;                                         \
                const float m0 = (v < (s)) ? g0 : 0.0f;                       \
                const float m1 = (v >= (s) - 4 && v <= 251) ? g1 : 0.0f;      \
                float x = ((const float*)&sd)[c] * md;                        \
                x = fmaf(m0, ((const float*)&sg0)[c], x);                     \
                x = fmaf(m1, ((const float*)&sg1)[c], x);                     \
                nu[c] += x;                                                   \
                de[c] += md + m0 + m1;                                        \
            }                                                                 \
        }
        SCALE_F(heat32, seg32, 32, 3, 8)
        SCALE_F(heat16, seg16, 16, 4, 16)
        SCALE_F(heat8,  seg8,  8,  5, 32)
#undef SCALE_F
    } else {
        // generic: full 2x2 preimage with masks
        const int i0  = u;
        const int i1c = min(u + 4, 255);
#define SCALE_G(heat, seg, g, l, s)                                           \
        {                                                                     \
            const float* __restrict__ h1 = heat + b * (g * g);                \
            const float* __restrict__ h2 = heat + (NB + b) * (g * g);         \
            const float* __restrict__ r1 = seg + (size_t)b * IMG2 + u * IMG;  \
            const float* __restrict__ ra =                                    \
                seg + (size_t)(NB + b) * IMG2 + i0 * IMG;                     \
            const float* __restrict__ rb =                                    \
                seg + (size_t)(NB + b) * IMG2 + i1c * IMG;                    \
            const float4 sd  = *(const float4*)(r1 + v0);                     \
            const float4 a0q = *(const float4*)(ra + v0);                     \
            const float4 a1q = *(const float4*)(ra + vs);                     \
            const float4 b0q = *(const float4*)(rb + v0);                     \
            const float4 b1q = *(const float4*)(rb + vs);                     \
            const float hd  = h1[(u >> l) * g + (v0 >> l)];                   \
            const float hA0 = h2[(i0 >> l) * g + (v0 >> l)];                  \
            const float hA1 = h2[(i0 >> l) * g + (vs >> l)];                  \
            const float hB0 = h2[(i1c >> l) * g + (v0 >> l)];                 \
            const float hB1 = h2[(i1c >> l) * g + (vs >> l)];                 \
            const float miA = (u < (s)) ? 1.0f : 0.0f;                        \
            const float miB = (u >= (s) - 4 && u <= 251) ? 1.0f : 0.0f;       \
            const float md  = (hd > 0.5f) ? 1.0f : 0.0f;                      \
            const float gA0 = miA * ((hA0 > 0.5f) ? 1.0f : 0.0f);             \
            const float gA1 = miA * ((hA1 > 0.5f) ? 1.0f : 0.0f);             \
            const float gB0 = miB * ((hB0 > 0.5f) ? 1.0f : 0.0f);             \
            const float gB1 = miB * ((hB1 > 0.5f) ? 1.0f : 0.0f);             \
            _Pragma("unroll")                                                 \
            for (int c = 0; c < 4; ++c) {                                     \
                const int v = v0 + c;                                         \
                const float mj0 = (v < (s)) ? 1.0f : 0.0f;                    \
                const float mj1 = (v >= (s) - 4 && v <= 251) ? 1.0f : 0.0f;   \
                const float w00 = gA0 * mj0, w01 = gA1 * mj1;                 \
                const float w10 = gB0 * mj0, w11 = gB1 * mj1;                 \
                float x = ((const float*)&sd)[c] * md;                        \
                x = fmaf(w00, ((const float*)&a0q)[c], x);                    \
                x = fmaf(w01, ((const float*)&a1q)[c], x);                    \
                x = fmaf(w10, ((const float*)&b0q)[c], x);                    \
                x = fmaf(w11, ((const float*)&b1q)[c], x);                    \
                nu[c] += x;                                                   \
                de[c] += md + w00 + w01 + w10 + w11;                          \
            }                                                                 \
        }
        SCALE_G(heat32, seg32, 32, 3, 8)
        SCALE_G(heat16, seg16, 16, 4, 16)
        SCALE_G(heat8,  seg8,  8,  5, 32)
#undef SCALE_G
    }

    float4 o;
    o.x = nu[0] / (de[0] + 1e-10f);
    o.y = nu[1] / (de[1] + 1e-10f);
    o.z = nu[2] / (de[2] + 1e-10f);
    o.w = nu[3] / (de[3] + 1e-10f);
    *(float4*)(out + (size_t)b * IMG2 + u * IMG + v0) = o;
}

__global__ __launch_bounds__(256) void fused_kernel(
    const float* __restrict__ img,
    const float* __restrict__ heat8,
    const float* __restrict__ heat16,
    const float* __restrict__ heat32,
    const float* __restrict__ seg8,
    const float* __restrict__ seg16,
    const float* __restrict__ seg32,
    float* __restrict__ out) {
    float* crops32 = out;                           // (128,1,256,256) s=8
    float* crops16 = out + (size_t)NB2 * IMG2;      // s=16
    float* crops8  = out + (size_t)2 * NB2 * IMG2;  // s=32
    float* label   = out + (size_t)3 * NB2 * IMG2;  // (64,1,256,256)

    const int bid = blockIdx.x;
    const int grp = bid / 13;
    const int rem = bid - grp * 13;

    if (rem < 9) {
        const int cb  = grp * 9 + rem;              // 0 .. 9215
        const int wid = cb * 4 + (threadIdx.x >> 6);
        if (cb < 4096) {
            crops_s8(img, heat32, crops32, wid);
        } else if (cb < 8192) {
            crops_s16(img, heat16, crops16, wid - 16384);
        } else {
            crops_s32(img, heat8, crops8, wid - 32768);
        }
    } else {
        const int lid = grp * 4 + (rem - 9);        // 0 .. 4095
        label_rows(heat8, heat16, heat32, seg8, seg16, seg32, label,
                   lid >> 6, (lid & 63) << 2);
    }
}

extern "C" void kernel_launch(void* const* d_in, const int* in_sizes, int n_in,
                              void* d_out, int out_size, void* d_ws, size_t ws_size,
                              hipStream_t stream) {
    const float* img    = (const float*)d_in[0];
    const float* heat8  = (const float*)d_in[1];
    const float* heat16 = (const float*)d_in[2];
    const float* heat32 = (const float*)d_in[3];
    const float* seg8   = (const float*)d_in[4];
    const float* seg16  = (const float*)d_in[5];
    const float* seg32  = (const float*)d_in[6];

    fused_kernel<<<dim3(NBLK_ALL), 256, 0, stream>>>(
        img, heat8, heat16, heat32, seg8, seg16, seg32, (float*)d_out);
}

// Round 4
// 223.656 us; speedup vs baseline: 1.0468x; 1.0026x over previous
//
#include <hip/hip_runtime.h>

#define IMG   256
#define IMG2  65536
#define NB    64
#define NB2   128

// ---------------------------------------------------------------------------
// Split into two kernels (diagnostic + structural): Round 0 (phase-ordered)
// and Round 3 (interleaved) timed identically, so co-residency of the crops
// and label populations is worth ~0 — splitting costs only a launch bubble
// and gives per-part rocprof counters.
//   crops_kernel: 9216 blocks x 256 (no LDS, no barriers)
//   label_kernel: 4096 blocks x 256 (1 wave per output row)
// ---------------------------------------------------------------------------

__device__ __forceinline__ float4 norm4(float4 a, float mn, float inv) {
    float4 o;
    o.x = (a.x - mn) * inv; o.y = (a.y - mn) * inv;
    o.z = (a.z - mn) * inv; o.w = (a.w - mn) * inv;
    return o;
}

__device__ __forceinline__ void mm4(float4 a, float& mn, float& mx) {
    mn = fminf(mn, fminf(fminf(a.x, a.y), fminf(a.z, a.w)));
    mx = fmaxf(mx, fmaxf(fmaxf(a.x, a.y), fmaxf(a.z, a.w)));
}

// S=8: wave handles a 4-cell strip (8 rows x 32 cols) of one cell-row.
// lane = r*8 + cell*2 + half  ->  cell-mates differ in bits {0,3,4,5}.
__device__ __forceinline__ void crops_s8(
    const float* __restrict__ img, const float* __restrict__ heat,
    float* __restrict__ out, int wid) {
    const int l   = threadIdx.x & 63;
    const int src = wid >> 8;
    const int rem = wid & 255;
    const int ci  = rem >> 3;
    const int st  = rem & 7;

    const int r    = l >> 3;
    const int cj   = st * 4 + ((l >> 1) & 3);
    const int o    = (l & 1) * 4;
    const int rowA = ci * 8 + r;
    const int rowB = ((ci == 0) ? 0 : ci * 8 - 4) + r;
    const int colA = st * 32 + (l & 7) * 4;
    const int colB = ((cj == 0) ? 0 : cj * 8 - 4) + o;

    const float* __restrict__ sp = img + (size_t)src * IMG2;
    const float4 a  = *(const float4*)(sp + rowA * IMG + colA);
    const float4 bq = *(const float4*)(sp + rowB * IMG + colB);

    float mnA = 3.4e38f, mxA = -3.4e38f, mnB = 3.4e38f, mxB = -3.4e38f;
    mm4(a, mnA, mxA); mm4(bq, mnB, mxB);
#pragma unroll
    for (int k = 0; k < 4; ++k) {
        const int off = (k == 0) ? 1 : (4 << k);  // 1, 8, 16, 32
        mnA = fminf(mnA, __shfl_xor(mnA, off, 64));
        mxA = fmaxf(mxA, __shfl_xor(mxA, off, 64));
        mnB = fminf(mnB, __shfl_xor(mnB, off, 64));
        mxB = fmaxf(mxB, __shfl_xor(mxB, off, 64));
    }
    const float hA = heat[(size_t)src * 1024 + ci * 32 + cj];
    const float hB = heat[(size_t)(src + NB) * 1024 + ci * 32 + cj];
    const float invA = (hA > 0.5f ? 1.0f : 0.0f) / (mxA - mnA + 1e-5f);
    const float invB = (hB > 0.5f ? 1.0f : 0.0f) / (mxB - mnB + 1e-5f);

    const size_t p = (size_t)src * IMG2 + rowA * IMG + colA;
    *(float4*)(out + p)                      = norm4(a,  mnA, invA);
    *(float4*)(out + p + (size_t)NB * IMG2)  = norm4(bq, mnB, invB);
}

// S=16: wave = one 16x16 cell; lane = r*4 + quarter.
__device__ __forceinline__ void crops_s16(
    const float* __restrict__ img, const float* __restrict__ heat,
    float* __restrict__ out, int wid) {
    const int l   = threadIdx.x & 63;
    const int src = wid >> 8;
    const int rem = wid & 255;
    const int ci  = rem >> 4;
    const int cj  = rem & 15;

    const int r    = l >> 2;
    const int o    = (l & 3) * 4;
    const int rowA = ci * 16 + r;
    const int rowB = ((ci == 0) ? 0 : ci * 16 - 4) + r;
    const int colA = cj * 16 + o;
    const int colB = ((cj == 0) ? 0 : cj * 16 - 4) + o;

    const float* __restrict__ sp = img + (size_t)src * IMG2;
    const float4 a  = *(const float4*)(sp + rowA * IMG + colA);
    const float4 bq = *(const float4*)(sp + rowB * IMG + colB);

    float mnA = 3.4e38f, mxA = -3.4e38f, mnB = 3.4e38f, mxB = -3.4e38f;
    mm4(a, mnA, mxA); mm4(bq, mnB, mxB);
#pragma unroll
    for (int off = 1; off < 64; off <<= 1) {
        mnA = fminf(mnA, __shfl_xor(mnA, off, 64));
        mxA = fmaxf(mxA, __shfl_xor(mxA, off, 64));
        mnB = fminf(mnB, __shfl_xor(mnB, off, 64));
        mxB = fmaxf(mxB, __shfl_xor(mxB, off, 64));
    }
    const float hA = heat[(size_t)src * 256 + ci * 16 + cj];
    const float hB = heat[(size_t)(src + NB) * 256 + ci * 16 + cj];
    const float invA = (hA > 0.5f ? 1.0f : 0.0f) / (mxA - mnA + 1e-5f);
    const float invB = (hB > 0.5f ? 1.0f : 0.0f) / (mxB - mnB + 1e-5f);

    const size_t p = (size_t)src * IMG2 + rowA * IMG + colA;
    *(float4*)(out + p)                      = norm4(a,  mnA, invA);
    *(float4*)(out + p + (size_t)NB * IMG2)  = norm4(bq, mnB, invB);
}

// S=32: wave = one 32x32 cell, 4 row-iterations held in registers.
__device__ __forceinline__ void crops_s32(
    const float* __restrict__ img, const float* __restrict__ heat,
    float* __restrict__ out, int wid) {
    const int l   = threadIdx.x & 63;
    const int src = wid >> 6;
    const int rem = wid & 63;
    const int ci  = rem >> 3;
    const int cj  = rem & 7;

    const int r0   = l >> 3;
    const int o    = (l & 7) * 4;
    const int rA   = ci * 32;
    const int rB   = (ci == 0) ? 0 : rA - 4;
    const int colA = cj * 32 + o;
    const int colB = ((cj == 0) ? 0 : cj * 32 - 4) + o;

    const float* __restrict__ sp = img + (size_t)src * IMG2;
    float4 a[4], bq[4];
#pragma unroll
    for (int k = 0; k < 4; ++k) {
        const int r = r0 + 8 * k;
        a[k]  = *(const float4*)(sp + (rA + r) * IMG + colA);
        bq[k] = *(const float4*)(sp + (rB + r) * IMG + colB);
    }
    float mnA = 3.4e38f, mxA = -3.4e38f, mnB = 3.4e38f, mxB = -3.4e38f;
#pragma unroll
    for (int k = 0; k < 4; ++k) { mm4(a[k], mnA, mxA); mm4(bq[k], mnB, mxB); }
#pragma unroll
    for (int off = 1; off < 64; off <<= 1) {
        mnA = fminf(mnA, __shfl_xor(mnA, off, 64));
        mxA = fmaxf(mxA, __shfl_xor(mxA, off, 64));
        mnB = fminf(mnB, __shfl_xor(mnB, off, 64));
        mxB = fmaxf(mxB, __shfl_xor(mxB, off, 64));
    }
    const float hA = heat[(size_t)src * 64 + ci * 8 + cj];
    const float hB = heat[(size_t)(src + NB) * 64 + ci * 8 + cj];
    const float invA = (hA > 0.5f ? 1.0f : 0.0f) / (mxA - mnA + 1e-5f);
    const float invB = (hB > 0.5f ? 1.0f : 0.0f) / (mxB - mnB + 1e-5f);

    float* __restrict__ dA = out + (size_t)src * IMG2;
    float* __restrict__ dB = out + (size_t)(src + NB) * IMG2;
#pragma unroll
    for (int k = 0; k < 4; ++k) {
        const int r = r0 + 8 * k;
        *(float4*)(dA + (rA + r) * IMG + colA) = norm4(a[k],  mnA, invA);
        *(float4*)(dB + (rA + r) * IMG + colA) = norm4(bq[k], mnB, invB);
    }
}

// ---------------------------------------------------------------------------
// label: one wave per row, 4 px per lane, float4 loads/stores.
// ---------------------------------------------------------------------------
__device__ __forceinline__ void label_rows(
    const float* __restrict__ heat8,
    const float* __restrict__ heat16,
    const float* __restrict__ heat32,
    const float* __restrict__ seg8,
    const float* __restrict__ seg16,
    const float* __restrict__ seg32,
    float* __restrict__ out,
    int b, int u0) {
    const int wave = threadIdx.x >> 6;
    const int lane = threadIdx.x & 63;
    const int u    = u0 + wave;
    const int v0   = lane << 2;
    const int vs   = min(v0 + 4, 252);   // shifted-load base, clamped

    float nu[4] = {0.f, 0.f, 0.f, 0.f};
    float de[4] = {0.f, 0.f, 0.f, 0.f};

    if (u0 >= 32 && u0 <= 248) {
        // fast: only preimage row i = u+4 exists for every scale
        const int i1 = u + 4;
#define SCALE_F(heat, seg, g, l, s)                                           \
        {                                                                     \
            const float* __restrict__ h1 = heat + b * (g * g);                \
            const float* __restrict__ h2 = heat + (NB + b) * (g * g);         \
            const float* __restrict__ r1 = seg + (size_t)b * IMG2 + u * IMG;  \
            const float* __restrict__ r2 =                                    \
                seg + (size_t)(NB + b) * IMG2 + i1 * IMG;                     \
            const float4 sd  = *(const float4*)(r1 + v0);                     \
            const float4 sg0 = *(const float4*)(r2 + v0);                     \
            const float4 sg1 = *(const float4*)(r2 + vs);                     \
            const float hd  = h1[(u >> l) * g + (v0 >> l)];                   \
            const float hg0 = h2[(i1 >> l) * g + (v0 >> l)];                  \
            const float hg1 = h2[(i1 >> l) * g + (vs >> l)];                  \
            const float md = (hd > 0.5f) ? 1.0f : 0.0f;                       \
            const float g0 = (hg0 > 0.5f) ? 1.0f : 0.0f;                      \
            const float g1 = (hg1 > 0.5f) ? 1.0f : 0.0f;                      \
            _Pragma("unroll")                                                 \
            for (int c = 0; c < 4; ++c) {                                     \
                const int v = v0 + c;                                         \
                const float m0 = (v < (s)) ? g0 : 0.0f;                       \
                const float m1 = (v >= (s) - 4 && v <= 251) ? g1 : 0.0f;      \
                float x = ((const float*)&sd)[c] * md;                        \
                x = fmaf(m0, ((const float*)&sg0)[c], x);                     \
                x = fmaf(m1, ((const float*)&sg1)[c], x);                     \
                nu[c] += x;                                                   \
                de[c] += md + m0 + m1;                                        \
            }                                                                 \
        }
        SCALE_F(heat32, seg32, 32, 3, 8)
        SCALE_F(heat16, seg16, 16, 4, 16)
        SCALE_F(heat8,  seg8,  8,  5, 32)
#undef SCALE_F
    } else {
        // generic: full 2x2 preimage with masks
        const int i0  = u;
        const int i1c = min(u + 4, 255);
#define SCALE_G(heat, seg, g, l, s)                                           \
        {                                                                     \
            const float* __restrict__ h1 = heat + b * (g * g);                \
            const float* __restrict__ h2 = heat + (NB + b) * (g * g);         \
            const float* __restrict__ r1 = seg + (size_t)b * IMG2 + u * IMG;  \
            const float* __restrict__ ra =                                    \
                seg + (size_t)(NB + b) * IMG2 + i0 * IMG;                     \
            const float* __restrict__ rb =                                    \
                seg + (size_t)(NB + b) * IMG2 + i1c * IMG;                    \
            const float4 sd  = *(const float4*)(r1 + v0);                     \
            const float4 a0q = *(const float4*)(ra + v0);                     \
            const float4 a1q = *(const float4*)(ra + vs);                     \
            const float4 b0q = *(const float4*)(rb + v0);                     \
            const float4 b1q = *(const float4*)(rb + vs);                     \
            const float hd  = h1[(u >> l) * g + (v0 >> l)];                   \
            const float hA0 = h2[(i0 >> l) * g + (v0 >> l)];                  \
            const float hA1 = h2[(i0 >> l) * g + (vs >> l)];                  \
            const float hB0 = h2[(i1c >> l) * g + (v0 >> l)];                 \
            const float hB1 = h2[(i1c >> l) * g + (vs >> l)];                 \
            const float miA = (u < (s)) ? 1.0f : 0.0f;                        \
            const float miB = (u >= (s) - 4 && u <= 251) ? 1.0f : 0.0f;       \
            const float md  = (hd > 0.5f) ? 1.0f : 0.0f;                      \
            const float gA0 = miA * ((hA0 > 0.5f) ? 1.0f : 0.0f);             \
            const float gA1 = miA * ((hA1 > 0.5f) ? 1.0f : 0.0f);             \
            const float gB0 = miB * ((hB0 > 0.5f) ? 1.0f : 0.0f);             \
            const float gB1 = miB * ((hB1 > 0.5f) ? 1.0f : 0.0f);             \
            _Pragma("unroll")                                                 \
            for (int c = 0; c < 4; ++c) {                                     \
                const int v = v0 + c;                                         \
                const float mj0 = (v < (s)) ? 1.0f : 0.0f;                    \
                const float mj1 = (v >= (s) - 4 && v <= 251) ? 1.0f : 0.0f;   \
                const float w00 = gA0 * mj0, w01 = gA1 * mj1;                 \
                const float w10 = gB0 * mj0, w11 = gB1 * mj1;                 \
                float x = ((const float*)&sd)[c] * md;                        \
                x = fmaf(w00, ((const float*)&a0q)[c], x);                    \
                x = fmaf(w01, ((const float*)&a1q)[c], x);                    \
                x = fmaf(w10, ((const float*)&b0q)[c], x);                    \
                x = fmaf(w11, ((const float*)&b1q)[c], x);                    \
                nu[c] += x;                                                   \
                de[c] += md + w00 + w01 + w10 + w11;                          \
            }                                                                 \
        }
        SCALE_G(heat32, seg32, 32, 3, 8)
        SCALE_G(heat16, seg16, 16, 4, 16)
        SCALE_G(heat8,  seg8,  8,  5, 32)
#undef SCALE_G
    }

    float4 o;
    o.x = nu[0] / (de[0] + 1e-10f);
    o.y = nu[1] / (de[1] + 1e-10f);
    o.z = nu[2] / (de[2] + 1e-10f);
    o.w = nu[3] / (de[3] + 1e-10f);
    *(float4*)(out + (size_t)b * IMG2 + u * IMG + v0) = o;
}

__global__ __launch_bounds__(256) void crops_kernel(
    const float* __restrict__ img,
    const float* __restrict__ heat8,
    const float* __restrict__ heat16,
    const float* __restrict__ heat32,
    float* __restrict__ out) {
    float* crops32 = out;                           // (128,1,256,256) s=8
    float* crops16 = out + (size_t)NB2 * IMG2;      // s=16
    float* crops8  = out + (size_t)2 * NB2 * IMG2;  // s=32

    const int cb  = blockIdx.x;                     // 0 .. 9215
    const int wid = cb * 4 + (threadIdx.x >> 6);
    if (cb < 4096) {
        crops_s8(img, heat32, crops32, wid);
    } else if (cb < 8192) {
        crops_s16(img, heat16, crops16, wid - 16384);
    } else {
        crops_s32(img, heat8, crops8, wid - 32768);
    }
}

__global__ __launch_bounds__(256) void label_kernel(
    const float* __restrict__ heat8,
    const float* __restrict__ heat16,
    const float* __restrict__ heat32,
    const float* __restrict__ seg8,
    const float* __restrict__ seg16,
    const float* __restrict__ seg32,
    float* __restrict__ out) {
    float* label = out + (size_t)3 * NB2 * IMG2;    // (64,1,256,256)
    const int t  = blockIdx.x;                      // 0 .. 4095
    label_rows(heat8, heat16, heat32, seg8, seg16, seg32, label,
               t >> 6, (t & 63) << 2);
}

extern "C" void kernel_launch(void* const* d_in, const int* in_sizes, int n_in,
                              void* d_out, int out_size, void* d_ws, size_t ws_size,
                              hipStream_t stream) {
    const float* img    = (const float*)d_in[0];
    const float* heat8  = (const float*)d_in[1];
    const float* heat16 = (const float*)d_in[2];
    const float* heat32 = (const float*)d_in[3];
    const float* seg8   = (const float*)d_in[4];
    const float* seg16  = (const float*)d_in[5];
    const float* seg32  = (const float*)d_in[6];

    label_kernel<<<dim3(4096), 256, 0, stream>>>(
        heat8, heat16, heat32, seg8, seg16, seg32, (float*)d_out);
    crops_kernel<<<dim3(9216), 256, 0, stream>>>(
        img, heat8, heat16, heat32, (float*)d_out);
}